// Round 3
// baseline (290.640 us; speedup 1.0000x reference)
//
#include <hip/hip_runtime.h>

typedef __attribute__((ext_vector_type(4))) float f32x4;
typedef __attribute__((ext_vector_type(8))) short bf16x8;
typedef __attribute__((ext_vector_type(4))) unsigned int u32x4;

static __device__ __forceinline__ unsigned short f2bf(float f) {
  union { float f; unsigned int u; } v;
  v.f = f;
  unsigned int r = v.u + 0x7fffu + ((v.u >> 16) & 1u);  // RNE
  return (unsigned short)(r >> 16);
}
static __device__ __forceinline__ unsigned packbf(float a, float b) {
  return (unsigned)f2bf(a) | ((unsigned)f2bf(b) << 16);
}
static __device__ __forceinline__ void gload16(const void* g, void* l) {
  __builtin_amdgcn_global_load_lds(
      (const __attribute__((address_space(1))) unsigned int*)g,
      (__attribute__((address_space(3))) unsigned int*)l, 16, 0, 0);
}

#define SBAR()   __builtin_amdgcn_s_barrier()
#define SCHED0() __builtin_amdgcn_sched_barrier(0)
#define WAITVM(N) do { asm volatile("s_waitcnt vmcnt(" #N ")" ::: "memory"); SCHED0(); } while (0)

// ---------------------------------------------------------------------------
// LSQ 4-bit fake-quant + pack to fragment-linear bf16.
// lane l holds wq[n][k], n = cf*16 + (l&15), k = ks*32 + (l>>4)*8 + j.
// w1 addr: ((cf*8 + ks)*64 + l)*8   (cf-major -> 16KB cf-pair chunks)
// w2 addr: ((ks*16 + cf)*64 + l)*8  (ks-major -> 16KB ks-slice chunks)
// ---------------------------------------------------------------------------
__global__ void lsq_pack(const float* __restrict__ w1, const float* __restrict__ a1,
                         const float* __restrict__ w2, const float* __restrict__ a2,
                         unsigned short* __restrict__ pq)
{
  int g = blockIdx.x * 256 + threadIdx.x;     // 0..16383
  int gg = g & 8191;
  const float* w = (g < 8192) ? w1 : w2;
  float alpha = (g < 8192) ? *a1 : *a2;
  unsigned short* dst = pq + ((g < 8192) ? 0 : 65536);
  int l  = gg & 63;
  int ks = (gg >> 6) & 7;
  int cf = gg >> 9;
  int n  = cf * 16 + (l & 15);
  int kb = ks * 32 + (l >> 4) * 8;
  const float* src = w + n * 256 + kb;
  unsigned short e[8];
  #pragma unroll
  for (int j = 0; j < 8; ++j) {
    float q = src[j] / alpha;
    q = fminf(fmaxf(q, -8.f), 7.f);
    q = rintf(q) * alpha;                     // round-half-even == jnp.round
    e[j] = f2bf(q);
  }
  uint4 o;
  o.x = e[0] | ((unsigned)e[1] << 16);
  o.y = e[2] | ((unsigned)e[3] << 16);
  o.z = e[4] | ((unsigned)e[5] << 16);
  o.w = e[6] | ((unsigned)e[7] << 16);
  int di = (g < 8192) ? ((cf * 8 + ks) * 64 + l) : ((ks * 16 + cf) * 64 + l);
  *(uint4*)(dst + di * 8) = o;
}

// ---------------------------------------------------------------------------
// Fused: out = sigmoid(relu(x@wq1^T + b1) @ wq2^T + b2)
// 256 thr (4 waves), wave-tile 32 rows, block-tile 128 rows, 1 block/CU.
// x(t+1) streamed fp32 -> 128KB LDS via global_load_lds, 2 slices/phase,
// kept in flight with counted vmcnt(2) + raw barriers (never drained mid-tile).
// Weights: 16KB chunks, slot0=w1(cf-pair), slot1=w2(ks-slice), staged one
// phase ahead. h transposed C-layout -> B-frag in-register via ds_bpermute.
// LDS: 128K x + 2*16K w = 163840 B exactly.
// ---------------------------------------------------------------------------
__global__ __launch_bounds__(256, 1) void lsq_fused(
    const float* __restrict__ x, const unsigned short* __restrict__ pqw,
    const float* __restrict__ b1, const float* __restrict__ b2,
    float* __restrict__ out, int ntiles)
{
  __shared__ __align__(16) char lds[163840];
  char* const xbuf  = lds;
  char* const slot0 = lds + 131072;   // w1 chunk (16KB)
  char* const slot1 = lds + 147456;   // w2 chunk (16KB)

  const int tid  = threadIdx.x;
  const int lane = tid & 63;
  const int w    = tid >> 6;
  const int l15  = lane & 15;
  const int l4   = lane >> 4;
  const char* pq1 = (const char*)pqw;
  const char* pq2 = (const char*)pqw + 131072;
  const int G = gridDim.x;
  const f32x4 fz = {0.f, 0.f, 0.f, 0.f};

  // Bias preload into registers (no global loads inside rounds -> vmcnt math holds).
  f32x4 bA0[8], bA1[8], bB[16];
  #pragma unroll
  for (int r = 0; r < 8; ++r) {
    bA0[r] = *(const f32x4*)(b1 + r * 32 + l4 * 4);
    bA1[r] = *(const f32x4*)(b1 + r * 32 + 16 + l4 * 4);
  }
  #pragma unroll
  for (int c2 = 0; c2 < 16; ++c2) bB[c2] = *(const f32x4*)(b2 + c2 * 16 + l4 * 4);

  // bpermute gather indices: src lane = ((l4&1)*2 + (wi>>1))*16 + l15
  int idx[4];
  #pragma unroll
  for (int wi = 0; wi < 4; ++wi)
    idx[wi] = (((l4 & 1) * 2 + (wi >> 1)) * 16 + l15) * 4;

  bf16x8 xf[2][8];
  auto CONVERT = [&]() {
    #pragma unroll
    for (int g = 0; g < 2; ++g) {
      const int row = w * 32 + g * 16 + l15;
      const int swz = (l15 & 7) << 4;          // row&7 == l15&7
      #pragma unroll
      for (int ks = 0; ks < 8; ++ks) {
        f32x4 r0 = *(const f32x4*)(xbuf + row * 1024 + ((ks * 128 + l4 * 32) ^ swz));
        f32x4 r1 = *(const f32x4*)(xbuf + row * 1024 + ((ks * 128 + l4 * 32 + 16) ^ swz));
        bf16x8 b;
        #pragma unroll
        for (int j = 0; j < 4; ++j) {
          b[j]     = (short)f2bf(r0[j]);
          b[j + 4] = (short)f2bf(r1[j]);
        }
        xf[g][ks] = b;
      }
    }
  };

  int t = blockIdx.x;

  // ---- prologue: stage x(tile t) fully + w1 chunk 0 ----
  {
    const char* xg = (const char*)x + (size_t)t * 131072;
    #pragma unroll
    for (int q = 0; q < 32; ++q) {
      const int row = q * 4 + w;
      gload16(xg + row * 1024 + ((lane * 16) ^ ((row & 7) << 4)), xbuf + row * 1024);
    }
    #pragma unroll
    for (int i = 0; i < 4; ++i) {
      const int sub = i * 4 + w;
      gload16(pq1 + sub * 1024 + lane * 16, slot0 + sub * 1024);
    }
  }
  WAITVM(0);
  SBAR();
  CONVERT();
  SBAR();          // no wave may start staging next x over xbuf until all converted

  f32x4 acc2[2][16];
  #pragma unroll
  for (int g = 0; g < 2; ++g)
    #pragma unroll
    for (int c2 = 0; c2 < 16; ++c2) acc2[g][c2] = fz;

  for (;;) {
    const int tn = (t + G < ntiles) ? (t + G) : t;   // clamp keeps issue counts constant
    const char* xgn = (const char*)x + (size_t)tn * 131072;

    #pragma unroll
    for (int r = 0; r < 8; ++r) {
      bf16x8 hf[2];
      // ================= phase A (uses slot0 = w1_r) =================
      if (r > 0) { WAITVM(2); SBAR(); }   // retires w1_r (issued last phase)
      #pragma unroll
      for (int i = 0; i < 4; ++i) {       // stage w2_r -> slot1
        const int sub = i * 4 + w;
        gload16(pq2 + r * 16384 + sub * 1024 + lane * 16, slot1 + sub * 1024);
      }
      SCHED0();                           // keep chunk-issues before xs-issues
      #pragma unroll
      for (int e = 0; e < 2; ++e) {       // 2 x-slices for tile tn
        const int row = (r * 4 + e) * 4 + w;
        gload16(xgn + row * 1024 + ((lane * 16) ^ ((row & 7) << 4)), xbuf + row * 1024);
      }
      // layer-1 MFMA for cf {2r, 2r+1}
      f32x4 aA[2][2] = {{fz, fz}, {fz, fz}};
      #pragma unroll
      for (int c = 0; c < 2; ++c)
        #pragma unroll
        for (int ks = 0; ks < 8; ++ks) {
          bf16x8 wf = *(const bf16x8*)(slot0 + c * 8192 + ks * 1024 + lane * 16);
          aA[c][0] = __builtin_amdgcn_mfma_f32_16x16x32_bf16(wf, xf[0][ks], aA[c][0], 0, 0, 0);
          aA[c][1] = __builtin_amdgcn_mfma_f32_16x16x32_bf16(wf, xf[1][ks], aA[c][1], 0, 0, 0);
        }
      // bias + relu + pack + in-register transpose (C-layout -> B-frag)
      #pragma unroll
      for (int g = 0; g < 2; ++g) {
        f32x4 v0, v1;
        #pragma unroll
        for (int j = 0; j < 4; ++j) {
          v0[j] = fmaxf(aA[0][g][j] + bA0[r][j], 0.f);
          v1[j] = fmaxf(aA[1][g][j] + bA1[r][j], 0.f);
        }
        const unsigned D0 = packbf(v0[0], v0[1]);
        const unsigned D1 = packbf(v0[2], v0[3]);
        const unsigned D2 = packbf(v1[0], v1[1]);
        const unsigned D3 = packbf(v1[2], v1[3]);
        unsigned hd[4];
        #pragma unroll
        for (int wi = 0; wi < 4; ++wi) {
          const int p0 = __builtin_amdgcn_ds_bpermute(idx[wi], (int)((wi & 1) ? D1 : D0));
          const int p1 = __builtin_amdgcn_ds_bpermute(idx[wi], (int)((wi & 1) ? D3 : D2));
          hd[wi] = (l4 >= 2) ? (unsigned)p1 : (unsigned)p0;
        }
        union { u32x4 u; bf16x8 v; } cv;
        cv.u[0] = hd[0]; cv.u[1] = hd[1]; cv.u[2] = hd[2]; cv.u[3] = hd[3];
        hf[g] = cv.v;
      }
      // ================= phase B (uses slot1 = w2_r) =================
      WAITVM(2); SBAR();                  // retires w2_r
      #pragma unroll
      for (int i = 0; i < 4; ++i) {       // stage w1_{(r+1)&7} -> slot0
        const int sub = i * 4 + w;
        gload16(pq1 + ((r + 1) & 7) * 16384 + sub * 1024 + lane * 16, slot0 + sub * 1024);
      }
      SCHED0();
      #pragma unroll
      for (int e = 0; e < 2; ++e) {
        const int row = (r * 4 + 2 + e) * 4 + w;
        gload16(xgn + row * 1024 + ((lane * 16) ^ ((row & 7) << 4)), xbuf + row * 1024);
      }
      // layer-2 partial, ks2 = r
      #pragma unroll
      for (int c2 = 0; c2 < 16; ++c2) {
        bf16x8 wf2 = *(const bf16x8*)(slot1 + c2 * 1024 + lane * 16);
        acc2[0][c2] = __builtin_amdgcn_mfma_f32_16x16x32_bf16(wf2, hf[0], acc2[0][c2], 0, 0, 0);
        acc2[1][c2] = __builtin_amdgcn_mfma_f32_16x16x32_bf16(wf2, hf[1], acc2[1][c2], 0, 0, 0);
      }
    } // rounds

    // ---- tile boundary: drain all DMA (x[tn] + w1_0'), sync, convert ----
    WAITVM(0); SBAR();
    const bool last = (t + G >= ntiles);
    if (!last) { CONVERT(); }
    SBAR();      // no wave starts next tile's x staging until all converted

    // epilogue: bias2 + sigmoid + store tile t; re-zero acc
    {
      const size_t rb = (size_t)t * 128 + w * 32;
      #pragma unroll
      for (int g = 0; g < 2; ++g) {
        float* op = out + (rb + g * 16 + l15) * 256 + l4 * 4;
        #pragma unroll
        for (int c2 = 0; c2 < 16; ++c2) {
          f32x4 o;
          #pragma unroll
          for (int j = 0; j < 4; ++j) {
            const float z = acc2[g][c2][j] + bB[c2][j];
            o[j] = 1.f / (1.f + __expf(-z));
          }
          *(f32x4*)(op + c2 * 16) = o;
          acc2[g][c2] = fz;
        }
      }
    }
    if (last) break;
    t = tn;
  }
}

// ---------------------------------------------------------------------------
extern "C" void kernel_launch(void* const* d_in, const int* in_sizes, int n_in,
                              void* d_out, int out_size, void* d_ws, size_t ws_size,
                              hipStream_t stream)
{
  const float* x  = (const float*)d_in[0];
  const float* w1 = (const float*)d_in[1];
  const float* b1 = (const float*)d_in[2];
  const float* a1 = (const float*)d_in[3];
  const float* w2 = (const float*)d_in[4];
  const float* b2 = (const float*)d_in[5];
  const float* a2 = (const float*)d_in[6];
  float* out = (float*)d_out;
  (void)ws_size;

  unsigned short* pq = (unsigned short*)d_ws;   // 256 KB packed weights

  long long totalRows = (long long)in_sizes[0] / 256;
  int ntiles = (int)(totalRows / 128);          // 2048 at N=262144

  lsq_pack<<<64, 256, 0, stream>>>(w1, a1, w2, a2, pq);

  int grid = ntiles < 256 ? ntiles : 256;
  lsq_fused<<<grid, 256, 0, stream>>>(x, pq, b1, b2, out, ntiles);
}